// Round 1
// baseline (515.079 us; speedup 1.0000x reference)
//
#include <hip/hip_runtime.h>
#include <stdint.h>

#define FP8_MAX 448.0f

typedef float floatx4 __attribute__((ext_vector_type(4)));
typedef long  longx2  __attribute__((ext_vector_type(2)));

// ---- async global->LDS 16B copy (global_load_lds_dwordx4) ----
// HW writes LDS at wave-uniform base + lane*16 (dest layout is forced linear);
// the GLOBAL source address is per-lane free, which is how we build the
// swizzled LDS layout below.
__device__ __forceinline__ void async_copy16(const void* g, void* s) {
    __builtin_amdgcn_global_load_lds(
        (const __attribute__((address_space(1))) void*)g,
        (__attribute__((address_space(3))) void*)s,
        16, 0, 0);
}

// ---- fp8 e4m3 quantization: dst[i] = fp8(clamp(src[i]*inv_scale, +-448)) ----
// Grid-stride, 16B/lane fully-coalesced loads (lane i -> base + i*16B),
// 4B/lane coalesced stores.
__global__ void __launch_bounds__(256) quant_fp8_kernel(
    const float* __restrict__ src, const float* __restrict__ scale,
    uint8_t* __restrict__ dst, long n4)
{
    float inv = 1.0f;
    if (scale) inv = 1.0f / scale[0];   // uniform scalar load + div
    const long stride = (long)gridDim.x * 256;
    for (long g = (long)blockIdx.x * 256 + threadIdx.x; g < n4; g += stride) {
        float4 v = ((const float4*)src)[g];
        float a = fminf(fmaxf(v.x * inv, -FP8_MAX), FP8_MAX);
        float b = fminf(fmaxf(v.y * inv, -FP8_MAX), FP8_MAX);
        float c = fminf(fmaxf(v.z * inv, -FP8_MAX), FP8_MAX);
        float d = fminf(fmaxf(v.w * inv, -FP8_MAX), FP8_MAX);
        int pk = 0;
        pk = __builtin_amdgcn_cvt_pk_fp8_f32(a, b, pk, false);  // bytes 0..1
        pk = __builtin_amdgcn_cvt_pk_fp8_f32(c, d, pk, true);   // bytes 2..3
        ((int*)dst)[g] = pk;
    }
}

// ---- fp8 GEMM, m97/m145 structure, bank-balanced lane-linear LDS reads ----
// A: qx [M][K] fp8 row-major, B: qw [N][K] fp8 row-major (B^T, K-contig)
// C[m][n] = sum_k A[m][k]*B[n][k];  out = C*osc + bias[n]
// Block tile 128x128, BK=64; 256 threads = 4 waves (2x2), each wave 64x64
// via 4x4 grid of mfma_f32_16x16x32_fp8_fp8.
//
// LDS layout (the round-1 fix): the tile is stored as 8 sub-tiles of
// 16 rows x 64B, each sub-tile = 64 slots of 16B, slot S (within matrix):
//   row(S)    = ((S>>6)<<4) | (S&15)      (sub = S>>6, r16 = S&15)
//   kchunk(S) = (S>>4)&3                  (16B of the 64B K-step)
// global_load_lds writes slot S = staging-thread id linearly; we invert the
// mapping on the per-lane GLOBAL source address instead.
//
// Fragment read: addr = sub*1024 + lane*16 -> lane-LINEAR 1KB sweep; each
// half-wave (32 lanes) covers 512 contiguous bytes = all 32 banks x 4 words
// (true minimum). The old read (slot = 4*(lane&15)+(lane>>4)) put each
// half-wave on only 16 banks -> measured 4 extra conflict-cycles per
// ds_read_b128 (SQ_LDS_BANK_CONFLICT/reads = 4.0 exactly).
// Fragment register contents are BIT-IDENTICAL to the previous kernel:
// lane holds row sub*16+(lane&15), k-bytes (lane>>4)*16..+16; lo 8B feeds
// MFMA#0, hi 8B MFMA#1 — same k-permutation for A and B (dot-product
// invariant).
__global__ void __launch_bounds__(256, 2) gemm_fp8_kernel(
    const uint8_t* __restrict__ A, const uint8_t* __restrict__ B,
    const float* __restrict__ bias,
    const float* __restrict__ in_scale, const float* __restrict__ w_scale,
    float* __restrict__ C, int M, int N, int K)
{
    __shared__ __align__(16) uint8_t As[128 * 64];
    __shared__ __align__(16) uint8_t Bs[128 * 64];

    const int tid  = threadIdx.x;
    const int lane = tid & 63;
    const int wid  = tid >> 6;
    const int wm   = wid >> 1;       // wave row (0..1)
    const int wn   = wid & 1;        // wave col (0..1)
    const int m0   = blockIdx.y * 128;
    const int n0   = blockIdx.x * 128;

    const int mlane = lane & 15;     // MFMA row/col within 16
    const int quad  = lane >> 4;     // 0..3

    // staging: slot S=tid and S=tid+256 per matrix; invert swizzle on the
    // global source: row = ((S>>6)<<4)|(S&15), col = ((S>>4)&3)*16
    const int S0 = tid, S1 = tid + 256;
    const int rA0 = ((S0 >> 6) << 4) | (S0 & 15), cA0 = ((S0 >> 4) & 3) * 16;
    const int rA1 = ((S1 >> 6) << 4) | (S1 & 15), cA1 = ((S1 >> 4) & 3) * 16;

    const uint8_t* Ab = A + (size_t)m0 * K;
    const uint8_t* Bb = B + (size_t)n0 * K;

    floatx4 acc[4][4];
#pragma unroll
    for (int i = 0; i < 4; ++i)
#pragma unroll
        for (int j = 0; j < 4; ++j) acc[i][j] = (floatx4){0.f, 0.f, 0.f, 0.f};

    // lane-linear, bank-balanced b128 read offsets (bytes)
    const int aoff = (wm * 4) * 1024 + lane * 16;   // + mi*1024
    const int boff = (wn * 4) * 1024 + lane * 16;   // + ni*1024

    for (int kt = 0; kt < K; kt += 64) {
        async_copy16(Ab + (size_t)rA0 * K + kt + cA0, As + S0 * 16);
        async_copy16(Ab + (size_t)rA1 * K + kt + cA1, As + S1 * 16);
        async_copy16(Bb + (size_t)rA0 * K + kt + cA0, Bs + S0 * 16);
        async_copy16(Bb + (size_t)rA1 * K + kt + cA1, Bs + S1 * 16);
        __syncthreads();   // compiler emits vmcnt(0) drain before barrier

        longx2 av[4], bv[4];
#pragma unroll
        for (int mi = 0; mi < 4; ++mi)
            av[mi] = *(const longx2*)(As + aoff + mi * 1024);
#pragma unroll
        for (int ni = 0; ni < 4; ++ni)
            bv[ni] = *(const longx2*)(Bs + boff + ni * 1024);

#pragma unroll
        for (int mi = 0; mi < 4; ++mi)
#pragma unroll
            for (int ni = 0; ni < 4; ++ni)
                acc[mi][ni] = __builtin_amdgcn_mfma_f32_16x16x32_fp8_fp8(
                    av[mi].x, bv[ni].x, acc[mi][ni], 0, 0, 0);
#pragma unroll
        for (int mi = 0; mi < 4; ++mi)
#pragma unroll
            for (int ni = 0; ni < 4; ++ni)
                acc[mi][ni] = __builtin_amdgcn_mfma_f32_16x16x32_fp8_fp8(
                    av[mi].y, bv[ni].y, acc[mi][ni], 0, 0, 0);

        __syncthreads();   // protect LDS overwrite next iteration
    }

    const float osc = in_scale[0] * w_scale[0];

    // epilogue: C/D layout col = lane&15, row = quad*4 + reg
#pragma unroll
    for (int mi = 0; mi < 4; ++mi) {
#pragma unroll
        for (int ni = 0; ni < 4; ++ni) {
            const int gn = n0 + wn * 64 + ni * 16 + mlane;
            const float bvv = bias[gn];
#pragma unroll
            for (int r = 0; r < 4; ++r) {
                const int gm = m0 + wm * 64 + mi * 16 + quad * 4 + r;
                C[(size_t)gm * N + gn] = acc[mi][ni][r] * osc + bvv;
            }
        }
    }
}

extern "C" void kernel_launch(void* const* d_in, const int* in_sizes, int n_in,
                              void* d_out, int out_size, void* d_ws, size_t ws_size,
                              hipStream_t stream) {
    const float* x        = (const float*)d_in[0];  // [M][K]
    const float* weight   = (const float*)d_in[1];  // [N][K], fp8-grid values
    const float* w_scale  = (const float*)d_in[2];  // [1]
    const float* bias     = (const float*)d_in[3];  // [N]
    const float* in_scale = (const float*)d_in[4];  // [1]
    float* out = (float*)d_out;

    const int N = in_sizes[3];                 // D_OUT = 4096
    const int K = in_sizes[1] / N;             // D_IN  = 4096
    const int M = in_sizes[0] / K;             // N_TOK = 8192

    uint8_t* qx = (uint8_t*)d_ws;                          // M*K fp8 (32 MB)
    uint8_t* qw = (uint8_t*)d_ws + (size_t)M * K;          // N*K fp8 (16 MB)

    const long nx4 = (long)M * K / 4;
    const long nw4 = (long)N * K / 4;
    long bx = (nx4 + 255) / 256; if (bx > 2048) bx = 2048;
    long bw = (nw4 + 255) / 256; if (bw > 2048) bw = 2048;
    quant_fp8_kernel<<<(int)bx, 256, 0, stream>>>(x, in_scale, qx, nx4);
    quant_fp8_kernel<<<(int)bw, 256, 0, stream>>>(weight, nullptr, qw, nw4);

    dim3 grid(N / 128, M / 128);  // (32, 64)
    gemm_fp8_kernel<<<grid, 256, 0, stream>>>(qx, qw, bias, in_scale, w_scale,
                                              out, M, N, K);
}

// Round 2
// 435.349 us; speedup vs baseline: 1.1831x; 1.1831x over previous
//
#include <hip/hip_runtime.h>
#include <stdint.h>

#define FP8_MAX 448.0f

typedef float floatx4 __attribute__((ext_vector_type(4)));
typedef long  longx2  __attribute__((ext_vector_type(2)));

// ---- async global->LDS 16B copy (global_load_lds_dwordx4) ----
// HW writes LDS at wave-uniform base + lane*16 (dest layout forced linear);
// the GLOBAL source address is per-lane free — the XOR swizzle below is
// applied by permuting the source, keeping LDS writes linear (both-sides
// rule, m201 pattern).
__device__ __forceinline__ void async_copy16(const void* g, void* s) {
    __builtin_amdgcn_global_load_lds(
        (const __attribute__((address_space(1))) void*)g,
        (__attribute__((address_space(3))) void*)s,
        16, 0, 0);
}

// ---- fused fp8 e4m3 quantization of x (scaled) and w (unscaled) ----
// Grid-stride, 16B/lane coalesced loads, 4B/lane coalesced stores.
// nx4 (=8.39M) is an exact multiple of stride (=524288), so the x/w branch
// is uniform across every wave (no divergence), and fusing the two passes
// saves a launch + lets both streams share the BW window.
__global__ void __launch_bounds__(256) quant_fp8_kernel(
    const float* __restrict__ x, const float* __restrict__ w,
    const float* __restrict__ scale,
    uint8_t* __restrict__ qx, uint8_t* __restrict__ qw,
    long nx4, long ntot4)
{
    const float invx = 1.0f / scale[0];
    const long stride = (long)gridDim.x * 256;
    for (long g = (long)blockIdx.x * 256 + threadIdx.x; g < ntot4; g += stride) {
        const float4* src; int* dst; float inv; long idx;
        if (g < nx4) { src = (const float4*)x; dst = (int*)qx; inv = invx; idx = g; }
        else         { src = (const float4*)w; dst = (int*)qw; inv = 1.0f; idx = g - nx4; }
        float4 v = src[idx];
        float a = fminf(fmaxf(v.x * inv, -FP8_MAX), FP8_MAX);
        float b = fminf(fmaxf(v.y * inv, -FP8_MAX), FP8_MAX);
        float c = fminf(fmaxf(v.z * inv, -FP8_MAX), FP8_MAX);
        float d = fminf(fmaxf(v.w * inv, -FP8_MAX), FP8_MAX);
        int pk = 0;
        pk = __builtin_amdgcn_cvt_pk_fp8_f32(a, b, pk, false);  // bytes 0..1
        pk = __builtin_amdgcn_cvt_pk_fp8_f32(c, d, pk, true);   // bytes 2..3
        dst[idx] = pk;
    }
}

// ---- fp8 GEMM, m97/m145 structure, XOR-swizzled LDS (both-sides) ----
// A: qx [M][K] fp8 row-major, B: qw [N][K] fp8 row-major (B^T, K-contig)
// C[m][n] = sum_k A[m][k]*B[n][k];  out = C*osc + bias[n]
// Block tile 128x128, BK=64; 256 threads = 4 waves (2x2), each wave 64x64
// via 4x4 grid of mfma_f32_16x16x32_fp8_fp8.
//
// LDS layout (round-2): row-major 64B rows (slot S -> row S>>2), with the
// 16B k-chunk XOR-swizzled:   (row r, kchunk q) stored at chunk 4r + (q^(r&3)).
//  * staging: slot S = tid linear in LDS; source = row S>>2,
//    kchunk (S&3)^((S>>2)&3).  The 4 lanes of a row-group read a PERMUTATION
//    of one contiguous aligned 64B row segment -> coalescing identical to
//    the unswizzled round-0 kernel (16 x 64B segments/wave, NOT 64 x 16B
//    like round-1's layout which tanked vmem throughput).
//  * fragment read: addr = row*64 + (quad^(mlane&3))*16.  Bank enumeration:
//    bank_start = (16*(mlane&1) + 4*(quad^(mlane&3)))&31 -> each half-wave
//    covers all 32 banks x 4 words = the ds_read_b128 minimum.  Round-0's
//    unswizzled read hit 16 banks/half-wave = measured +4 cyc/read
//    (SQ_LDS_BANK_CONFLICT/reads was exactly 4.0).
// XOR is an involution -> every lane receives BIT-IDENTICAL fragment bytes
// to the round-0 kernel (row sub*16+mlane, k-bytes quad*16..+16; lo 8B ->
// MFMA#0, hi 8B -> MFMA#1; same k-permutation on A and B).
__global__ void __launch_bounds__(256, 2) gemm_fp8_kernel(
    const uint8_t* __restrict__ A, const uint8_t* __restrict__ B,
    const float* __restrict__ bias,
    const float* __restrict__ in_scale, const float* __restrict__ w_scale,
    float* __restrict__ C, int M, int N, int K)
{
    __shared__ __align__(16) uint8_t As[128 * 64];
    __shared__ __align__(16) uint8_t Bs[128 * 64];

    const int tid  = threadIdx.x;
    const int lane = tid & 63;
    const int wid  = tid >> 6;
    const int wm   = wid >> 1;       // wave row (0..1)
    const int wn   = wid & 1;        // wave col (0..1)
    const int m0   = blockIdx.y * 128;
    const int n0   = blockIdx.x * 128;

    const int mlane = lane & 15;     // MFMA row/col within 16
    const int quad  = lane >> 4;     // 0..3

    // staging: slot S -> global row S>>2, kchunk (S&3)^((S>>2)&3)
    const int S0 = tid, S1 = tid + 256;
    const int rA0 = S0 >> 2, cA0 = ((S0 & 3) ^ (rA0 & 3)) * 16;
    const int rA1 = S1 >> 2, cA1 = ((S1 & 3) ^ (rA1 & 3)) * 16;

    const uint8_t* Ab = A + (size_t)m0 * K;
    const uint8_t* Bb = B + (size_t)n0 * K;

    floatx4 acc[4][4];
#pragma unroll
    for (int i = 0; i < 4; ++i)
#pragma unroll
        for (int j = 0; j < 4; ++j) acc[i][j] = (floatx4){0.f, 0.f, 0.f, 0.f};

    // swizzled, conflict-free b128 read offsets (bytes); row&3 == mlane&3
    const int swz  = (quad ^ (mlane & 3)) * 16;
    const int aoff = (wm * 64 + mlane) * 64 + swz;   // + mi*1024
    const int boff = (wn * 64 + mlane) * 64 + swz;   // + ni*1024

    for (int kt = 0; kt < K; kt += 64) {
        async_copy16(Ab + (size_t)rA0 * K + kt + cA0, As + S0 * 16);
        async_copy16(Ab + (size_t)rA1 * K + kt + cA1, As + S1 * 16);
        async_copy16(Bb + (size_t)rA0 * K + kt + cA0, Bs + S0 * 16);
        async_copy16(Bb + (size_t)rA1 * K + kt + cA1, Bs + S1 * 16);
        __syncthreads();   // compiler emits vmcnt(0) drain before barrier

        longx2 av[4], bv[4];
#pragma unroll
        for (int mi = 0; mi < 4; ++mi)
            av[mi] = *(const longx2*)(As + aoff + mi * 1024);
#pragma unroll
        for (int ni = 0; ni < 4; ++ni)
            bv[ni] = *(const longx2*)(Bs + boff + ni * 1024);

#pragma unroll
        for (int mi = 0; mi < 4; ++mi)
#pragma unroll
            for (int ni = 0; ni < 4; ++ni)
                acc[mi][ni] = __builtin_amdgcn_mfma_f32_16x16x32_fp8_fp8(
                    av[mi].x, bv[ni].x, acc[mi][ni], 0, 0, 0);
#pragma unroll
        for (int mi = 0; mi < 4; ++mi)
#pragma unroll
            for (int ni = 0; ni < 4; ++ni)
                acc[mi][ni] = __builtin_amdgcn_mfma_f32_16x16x32_fp8_fp8(
                    av[mi].y, bv[ni].y, acc[mi][ni], 0, 0, 0);

        __syncthreads();   // protect LDS overwrite next iteration
    }

    const float osc = in_scale[0] * w_scale[0];

    // epilogue: C/D layout col = lane&15, row = quad*4 + reg
#pragma unroll
    for (int mi = 0; mi < 4; ++mi) {
#pragma unroll
        for (int ni = 0; ni < 4; ++ni) {
            const int gn = n0 + wn * 64 + ni * 16 + mlane;
            const float bvv = bias[gn];
#pragma unroll
            for (int r = 0; r < 4; ++r) {
                const int gm = m0 + wm * 64 + mi * 16 + quad * 4 + r;
                C[(size_t)gm * N + gn] = acc[mi][ni][r] * osc + bvv;
            }
        }
    }
}

extern "C" void kernel_launch(void* const* d_in, const int* in_sizes, int n_in,
                              void* d_out, int out_size, void* d_ws, size_t ws_size,
                              hipStream_t stream) {
    const float* x        = (const float*)d_in[0];  // [M][K]
    const float* weight   = (const float*)d_in[1];  // [N][K], fp8-grid values
    const float* w_scale  = (const float*)d_in[2];  // [1]
    const float* bias     = (const float*)d_in[3];  // [N]
    const float* in_scale = (const float*)d_in[4];  // [1]
    float* out = (float*)d_out;

    const int N = in_sizes[3];                 // D_OUT = 4096
    const int K = in_sizes[1] / N;             // D_IN  = 4096
    const int M = in_sizes[0] / K;             // N_TOK = 8192

    uint8_t* qx = (uint8_t*)d_ws;                          // M*K fp8 (32 MB)
    uint8_t* qw = (uint8_t*)d_ws + (size_t)M * K;          // N*K fp8 (16 MB)

    const long nx4   = (long)M * K / 4;        // 8388608, = 16 * 524288
    const long ntot4 = nx4 + (long)N * K / 4;  // + 4194304
    long blks = (ntot4 + 255) / 256; if (blks > 2048) blks = 2048;
    quant_fp8_kernel<<<(int)blks, 256, 0, stream>>>(x, weight, in_scale,
                                                    qx, qw, nx4, ntot4);

    dim3 grid(N / 128, M / 128);  // (32, 64)
    gemm_fp8_kernel<<<grid, 256, 0, stream>>>(qx, qw, bias, in_scale, w_scale,
                                              out, M, N, K);
}

// Round 3
// 420.285 us; speedup vs baseline: 1.2255x; 1.0358x over previous
//
#include <hip/hip_runtime.h>
#include <stdint.h>

#define FP8_MAX 448.0f

typedef float floatx16 __attribute__((ext_vector_type(16)));
typedef int   intx4    __attribute__((ext_vector_type(4)));
typedef int   intx8    __attribute__((ext_vector_type(8)));

// ---- async global->LDS 16B copy (global_load_lds_dwordx4) ----
// HW writes LDS at wave-uniform base + lane*16 (dest forced linear); the
// GLOBAL source address is per-lane free — swizzle applied on the source.
__device__ __forceinline__ void async_copy16(const void* g, void* s) {
    __builtin_amdgcn_global_load_lds(
        (const __attribute__((address_space(1))) void*)g,
        (__attribute__((address_space(3))) void*)s,
        16, 0, 0);
}

// ---- fused fp8 e4m3 quantization of x (scaled) and w (unscaled) ----
// Grid-stride, 16B/lane coalesced loads, 4B/lane coalesced stores.
// nx4 is an exact multiple of stride, so the x/w branch is wave-uniform.
__global__ void __launch_bounds__(256) quant_fp8_kernel(
    const float* __restrict__ x, const float* __restrict__ w,
    const float* __restrict__ scale,
    uint8_t* __restrict__ qx, uint8_t* __restrict__ qw,
    long nx4, long ntot4)
{
    const float invx = 1.0f / scale[0];
    const long stride = (long)gridDim.x * 256;
    for (long g = (long)blockIdx.x * 256 + threadIdx.x; g < ntot4; g += stride) {
        const float4* src; int* dst; float inv; long idx;
        if (g < nx4) { src = (const float4*)x; dst = (int*)qx; inv = invx; idx = g; }
        else         { src = (const float4*)w; dst = (int*)qw; inv = 1.0f; idx = g - nx4; }
        float4 v = src[idx];
        float a = fminf(fmaxf(v.x * inv, -FP8_MAX), FP8_MAX);
        float b = fminf(fmaxf(v.y * inv, -FP8_MAX), FP8_MAX);
        float c = fminf(fmaxf(v.z * inv, -FP8_MAX), FP8_MAX);
        float d = fminf(fmaxf(v.w * inv, -FP8_MAX), FP8_MAX);
        int pk = 0;
        pk = __builtin_amdgcn_cvt_pk_fp8_f32(a, b, pk, false);  // bytes 0..1
        pk = __builtin_amdgcn_cvt_pk_fp8_f32(c, d, pk, true);   // bytes 2..3
        dst[idx] = pk;
    }
}

// ---- fp8 GEMM via MX-scaled MFMA (unit scales), 128x128/BK=64 skeleton ----
// A: qx [M][K] fp8 row-major, B: qw [N][K] fp8 row-major (B^T, K-contig)
// C[m][n] = sum_k A[m][k]*B[n][k];  out = C*osc + bias[n]
// 256 threads = 4 waves (2x2), each wave a 64x64 sub-tile as a 2x2 grid of
// v_mfma_scale_f32_32x32x64_f8f6f4 (cbsz=0,blgp=0 -> fp8 e4m3 both; all
// e8m0 scales = 0x7F = 2^0, so math is bit-exact plain fp8 x fp8 -> f32,
// but at the MX rate: ~4686 TF vs 2047 TF for the non-scaled fp8 MFMA).
//
// Staging (byte-identical to the verified round-2 code, 190us): slot S ->
// global row S>>2, kchunk (S&3)^((S>>2)&3). The 4 lanes of a row-group read
// a permutation of one contiguous 64B row segment -> full coalescing.
//
// Fragment read (32x32x64 A-operand): lane holds row lane&31 of its 32-row
// block, k-bytes (lane>>5)*32..+32 -> two ds_read_b128 per fragment, at
// stored chunk (logical_chunk ^ (row&3)) (xor involution inverts staging).
// The +4cyc/read LDS conflicts on permuted b128 reads are measured
// non-critical (round 0 vs round 2: identical conflicts, identical time).
// All-1.0 scales also make the math invariant to any consistent A/B
// k-placement, de-risking the fragment map.
__global__ void __launch_bounds__(256, 2) gemm_fp8_kernel(
    const uint8_t* __restrict__ A, const uint8_t* __restrict__ B,
    const float* __restrict__ bias,
    const float* __restrict__ in_scale, const float* __restrict__ w_scale,
    float* __restrict__ C, int M, int N, int K)
{
    __shared__ __align__(16) uint8_t As[128 * 64];
    __shared__ __align__(16) uint8_t Bs[128 * 64];

    const int tid  = threadIdx.x;
    const int lane = tid & 63;
    const int wid  = tid >> 6;
    const int wm   = wid >> 1;       // wave row (0..1)
    const int wn   = wid & 1;        // wave col (0..1)
    const int m0   = blockIdx.y * 128;
    const int n0   = blockIdx.x * 128;

    const int rl = lane & 31;        // row/col within the 32-block
    const int h  = lane >> 5;        // k-half (0: k 0..31, 1: k 32..63)

    // staging: slot S -> global row S>>2, kchunk (S&3)^((S>>2)&3)
    const int S0 = tid, S1 = tid + 256;
    const int rA0 = S0 >> 2, cA0 = ((S0 & 3) ^ (rA0 & 3)) * 16;
    const int rA1 = S1 >> 2, cA1 = ((S1 & 3) ^ (rA1 & 3)) * 16;

    const uint8_t* Ab = A + (size_t)m0 * K;
    const uint8_t* Bb = B + (size_t)n0 * K;

    floatx16 acc[2][2];
#pragma unroll
    for (int i = 0; i < 2; ++i)
#pragma unroll
        for (int j = 0; j < 2; ++j)
#pragma unroll
            for (int r = 0; r < 16; ++r) acc[i][j][r] = 0.f;

    // fragment read offsets: logical chunks h*2 (s=0) and h*2+1 (s=1),
    // stored at (logical ^ (row&3)); row&3 == rl&3
    const int ca   = ((h * 2)     ^ (rl & 3)) * 16;
    const int cb   = ((h * 2 + 1) ^ (rl & 3)) * 16;
    const int aoff = (wm * 64 + rl) * 64;    // + mi*2048
    const int boff = (wn * 64 + rl) * 64;    // + ni*2048

    const int sOne = 0x7F7F7F7F;  // e8m0 = 127 -> 2^0 = 1.0 in every byte

    for (int kt = 0; kt < K; kt += 64) {
        async_copy16(Ab + (size_t)rA0 * K + kt + cA0, As + S0 * 16);
        async_copy16(Ab + (size_t)rA1 * K + kt + cA1, As + S1 * 16);
        async_copy16(Bb + (size_t)rA0 * K + kt + cA0, Bs + S0 * 16);
        async_copy16(Bb + (size_t)rA1 * K + kt + cA1, Bs + S1 * 16);
        __syncthreads();   // compiler emits vmcnt(0) drain before barrier

        intx8 av[2], bv[2];
#pragma unroll
        for (int mi = 0; mi < 2; ++mi) {
            intx4 lo = *(const intx4*)(As + aoff + mi * 2048 + ca);
            intx4 hi = *(const intx4*)(As + aoff + mi * 2048 + cb);
            av[mi] = (intx8){lo[0], lo[1], lo[2], lo[3],
                             hi[0], hi[1], hi[2], hi[3]};
        }
#pragma unroll
        for (int ni = 0; ni < 2; ++ni) {
            intx4 lo = *(const intx4*)(Bs + boff + ni * 2048 + ca);
            intx4 hi = *(const intx4*)(Bs + boff + ni * 2048 + cb);
            bv[ni] = (intx8){lo[0], lo[1], lo[2], lo[3],
                             hi[0], hi[1], hi[2], hi[3]};
        }

#pragma unroll
        for (int mi = 0; mi < 2; ++mi)
#pragma unroll
            for (int ni = 0; ni < 2; ++ni)
                acc[mi][ni] = __builtin_amdgcn_mfma_scale_f32_32x32x64_f8f6f4(
                    av[mi], bv[ni], acc[mi][ni],
                    0 /*cbsz: fp8 e4m3*/, 0 /*blgp: fp8 e4m3*/,
                    0, sOne, 0, sOne);

        __syncthreads();   // protect LDS overwrite next iteration
    }

    const float osc = in_scale[0] * w_scale[0];

    // epilogue: 32x32 C/D layout (m74/m101, shape-determined):
    // col = lane&31, row = (reg&3) + 8*(reg>>2) + 4*(lane>>5)
#pragma unroll
    for (int mi = 0; mi < 2; ++mi) {
#pragma unroll
        for (int ni = 0; ni < 2; ++ni) {
            const int gn = n0 + wn * 64 + ni * 32 + rl;
            const float bvv = bias[gn];
#pragma unroll
            for (int r = 0; r < 16; ++r) {
                const int row = (r & 3) + 8 * (r >> 2) + 4 * h;
                const int gm = m0 + wm * 64 + mi * 32 + row;
                C[(size_t)gm * N + gn] = acc[mi][ni][r] * osc + bvv;
            }
        }
    }
}

extern "C" void kernel_launch(void* const* d_in, const int* in_sizes, int n_in,
                              void* d_out, int out_size, void* d_ws, size_t ws_size,
                              hipStream_t stream) {
    const float* x        = (const float*)d_in[0];  // [M][K]
    const float* weight   = (const float*)d_in[1];  // [N][K], fp8-grid values
    const float* w_scale  = (const float*)d_in[2];  // [1]
    const float* bias     = (const float*)d_in[3];  // [N]
    const float* in_scale = (const float*)d_in[4];  // [1]
    float* out = (float*)d_out;

    const int N = in_sizes[3];                 // D_OUT = 4096
    const int K = in_sizes[1] / N;             // D_IN  = 4096
    const int M = in_sizes[0] / K;             // N_TOK = 8192

    uint8_t* qx = (uint8_t*)d_ws;                          // M*K fp8 (32 MB)
    uint8_t* qw = (uint8_t*)d_ws + (size_t)M * K;          // N*K fp8 (16 MB)

    const long nx4   = (long)M * K / 4;        // 8388608, = 16 * 524288
    const long ntot4 = nx4 + (long)N * K / 4;  // + 4194304
    long blks = (ntot4 + 255) / 256; if (blks > 2048) blks = 2048;
    quant_fp8_kernel<<<(int)blks, 256, 0, stream>>>(x, weight, in_scale,
                                                    qx, qw, nx4, ntot4);

    dim3 grid(N / 128, M / 128);  // (32, 64)
    gemm_fp8_kernel<<<grid, 256, 0, stream>>>(qx, qw, bias, in_scale, w_scale,
                                              out, M, N, K);
}

// Round 4
// 414.791 us; speedup vs baseline: 1.2418x; 1.0132x over previous
//
#include <hip/hip_runtime.h>
#include <stdint.h>

#define FP8_MAX 448.0f

typedef float floatx16 __attribute__((ext_vector_type(16)));
typedef int   intx4    __attribute__((ext_vector_type(4)));
typedef int   intx8    __attribute__((ext_vector_type(8)));

// ---- async global->LDS 16B copy (global_load_lds_dwordx4) ----
// HW writes LDS at wave-uniform base + lane*16 (dest forced linear); the
// GLOBAL source address is per-lane free — swizzle applied on the source.
__device__ __forceinline__ void async_copy16(const void* g, void* s) {
    __builtin_amdgcn_global_load_lds(
        (const __attribute__((address_space(1))) void*)g,
        (__attribute__((address_space(3))) void*)s,
        16, 0, 0);
}

// ---- fused fp8 e4m3 quantization of x (scaled) and w (unscaled) ----
// Grid-stride, 16B/lane coalesced loads, 4B/lane coalesced stores.
// nx4 is an exact multiple of stride, so the x/w branch is wave-uniform.
// (Non-gemm time is constant ~244us across 3 structurally different quant
// versions -> fixed overhead + ~40us BW-bound quant; not the lever.)
__global__ void __launch_bounds__(256) quant_fp8_kernel(
    const float* __restrict__ x, const float* __restrict__ w,
    const float* __restrict__ scale,
    uint8_t* __restrict__ qx, uint8_t* __restrict__ qw,
    long nx4, long ntot4)
{
    const float invx = 1.0f / scale[0];
    const long stride = (long)gridDim.x * 256;
    for (long g = (long)blockIdx.x * 256 + threadIdx.x; g < ntot4; g += stride) {
        const float4* src; int* dst; float inv; long idx;
        if (g < nx4) { src = (const float4*)x; dst = (int*)qx; inv = invx; idx = g; }
        else         { src = (const float4*)w; dst = (int*)qw; inv = 1.0f; idx = g - nx4; }
        float4 v = src[idx];
        float a = fminf(fmaxf(v.x * inv, -FP8_MAX), FP8_MAX);
        float b = fminf(fmaxf(v.y * inv, -FP8_MAX), FP8_MAX);
        float c = fminf(fmaxf(v.z * inv, -FP8_MAX), FP8_MAX);
        float d = fminf(fmaxf(v.w * inv, -FP8_MAX), FP8_MAX);
        int pk = 0;
        pk = __builtin_amdgcn_cvt_pk_fp8_f32(a, b, pk, false);  // bytes 0..1
        pk = __builtin_amdgcn_cvt_pk_fp8_f32(c, d, pk, true);   // bytes 2..3
        dst[idx] = pk;
    }
}

// ---- fp8 GEMM via MX-scaled MFMA (unit scales), 2-phase double-buffered ----
// A: qx [M][K] fp8 row-major, B: qw [N][K] fp8 row-major (B^T, K-contig)
// C[m][n] = sum_k A[m][k]*B[n][k];  out = C*osc + bias[n]
// Block tile 128x128, BK=64; 256 threads = 4 waves (2x2), each wave a 64x64
// sub-tile as 2x2 v_mfma_scale_f32_32x32x64_f8f6f4 (all e8m0 scales = 0x7F
// = 2^0 -> bit-exact plain fp8xfp8->f32 at the MX rate, ~4686 vs 2047 TF).
//
// Round-4 changes:
// 1) Swizzle fixed for the 32x32 read pattern: (row r, chunk q) stored at
//    chunk q ^ ((r>>1)&3).  Read sweeps 32 consecutive rows at fixed q, so
//    bank_start = 16*(r&1) + 4*(q^((r>>1)&3)) covers all 8 starts exactly
//    4x per half-wave (b128 minimum).  Round-3's q^(r&3) gave only 4 starts
//    -> 8-way groups -> measured 12 extra cyc/read (5.03e7 conflicts).
//    Staging unaffected: each 4-lane row-group still reads a permutation of
//    one contiguous 64B row segment (full coalescing).
// 2) T3 minimum 2-phase: double-buffered LDS, next-tile global_load_lds
//    issued BEFORE this tile's ds_read+MFMA, ONE __syncthreads (vmcnt(0)
//    drain + barrier) per K-step instead of two -> stage latency hides
//    under compute instead of stalling all waves before it.
__global__ void __launch_bounds__(256, 2) gemm_fp8_kernel(
    const uint8_t* __restrict__ A, const uint8_t* __restrict__ B,
    const float* __restrict__ bias,
    const float* __restrict__ in_scale, const float* __restrict__ w_scale,
    float* __restrict__ C, int M, int N, int K)
{
    __shared__ __align__(16) uint8_t As[2 * 128 * 64];   // 16 KB (2 bufs)
    __shared__ __align__(16) uint8_t Bs[2 * 128 * 64];   // 16 KB (2 bufs)

    const int tid  = threadIdx.x;
    const int lane = tid & 63;
    const int wid  = tid >> 6;
    const int wm   = wid >> 1;       // wave row (0..1)
    const int wn   = wid & 1;        // wave col (0..1)
    const int m0   = blockIdx.y * 128;
    const int n0   = blockIdx.x * 128;

    const int rl = lane & 31;        // row/col within the 32-block
    const int h  = lane >> 5;        // k-half (0: k 0..31, 1: k 32..63)

    // staging: slot S -> global row S>>2, logical chunk (S&3)^((row>>1)&3)
    // (involution of the store swizzle; row>>1 bits of S are S>>3)
    const int S0 = tid, S1 = tid + 256;
    const int rA0 = S0 >> 2, cA0 = ((S0 & 3) ^ ((S0 >> 3) & 3)) * 16;
    const int rA1 = S1 >> 2, cA1 = ((S1 & 3) ^ ((S1 >> 3) & 3)) * 16;

    const uint8_t* Ab = A + (size_t)m0 * K;
    const uint8_t* Bb = B + (size_t)n0 * K;

    floatx16 acc[2][2];
#pragma unroll
    for (int i = 0; i < 2; ++i)
#pragma unroll
        for (int j = 0; j < 2; ++j)
#pragma unroll
            for (int r = 0; r < 16; ++r) acc[i][j][r] = 0.f;

    // fragment reads: logical chunks h*2 (lo) / h*2+1 (hi), stored at
    // chunk ^ ((rl>>1)&3)
    const int fsw  = (rl >> 1) & 3;
    const int ca   = ((h * 2)     ^ fsw) * 16;
    const int cb   = ((h * 2 + 1) ^ fsw) * 16;
    const int aoff = (wm * 64 + rl) * 64;    // + mi*2048
    const int boff = (wn * 64 + rl) * 64;    // + ni*2048

    const int sOne = 0x7F7F7F7F;  // e8m0 = 127 -> 2^0 = 1.0 in every byte
    const int NS = K >> 6;        // K-steps

    // prologue: stage tile 0 into buffer 0
    async_copy16(Ab + (size_t)rA0 * K + cA0, As + S0 * 16);
    async_copy16(Ab + (size_t)rA1 * K + cA1, As + S1 * 16);
    async_copy16(Bb + (size_t)rA0 * K + cA0, Bs + S0 * 16);
    async_copy16(Bb + (size_t)rA1 * K + cA1, Bs + S1 * 16);
    __syncthreads();   // vmcnt(0) drain + barrier

    int cur = 0;
    for (int t = 0; t < NS; ++t) {
        // issue next-tile staging FIRST (into the other buffer)
        if (t + 1 < NS) {
            const int kt = (t + 1) << 6;
            const int nb = (cur ^ 1) * 8192;
            async_copy16(Ab + (size_t)rA0 * K + kt + cA0, As + nb + S0 * 16);
            async_copy16(Ab + (size_t)rA1 * K + kt + cA1, As + nb + S1 * 16);
            async_copy16(Bb + (size_t)rA0 * K + kt + cA0, Bs + nb + S0 * 16);
            async_copy16(Bb + (size_t)rA1 * K + kt + cA1, Bs + nb + S1 * 16);
        }

        const uint8_t* as = As + cur * 8192;
        const uint8_t* bs = Bs + cur * 8192;
        intx8 av[2], bv[2];
#pragma unroll
        for (int mi = 0; mi < 2; ++mi) {
            intx4 lo = *(const intx4*)(as + aoff + mi * 2048 + ca);
            intx4 hi = *(const intx4*)(as + aoff + mi * 2048 + cb);
            av[mi] = (intx8){lo[0], lo[1], lo[2], lo[3],
                             hi[0], hi[1], hi[2], hi[3]};
        }
#pragma unroll
        for (int ni = 0; ni < 2; ++ni) {
            intx4 lo = *(const intx4*)(bs + boff + ni * 2048 + ca);
            intx4 hi = *(const intx4*)(bs + boff + ni * 2048 + cb);
            bv[ni] = (intx8){lo[0], lo[1], lo[2], lo[3],
                             hi[0], hi[1], hi[2], hi[3]};
        }

#pragma unroll
        for (int mi = 0; mi < 2; ++mi)
#pragma unroll
            for (int ni = 0; ni < 2; ++ni)
                acc[mi][ni] = __builtin_amdgcn_mfma_scale_f32_32x32x64_f8f6f4(
                    av[mi], bv[ni], acc[mi][ni],
                    0 /*cbsz: fp8 e4m3*/, 0 /*blgp: fp8 e4m3*/,
                    0, sOne, 0, sOne);

        __syncthreads();   // vmcnt(0): next tile landed; barrier: reads done
        cur ^= 1;
    }

    const float osc = in_scale[0] * w_scale[0];

    // epilogue: 32x32 C/D layout (m74/m101, shape-determined):
    // col = lane&31, row = (reg&3) + 8*(reg>>2) + 4*(lane>>5)
#pragma unroll
    for (int mi = 0; mi < 2; ++mi) {
#pragma unroll
        for (int ni = 0; ni < 2; ++ni) {
            const int gn = n0 + wn * 64 + ni * 32 + rl;
            const float bvv = bias[gn];
#pragma unroll
            for (int r = 0; r < 16; ++r) {
                const int row = (r & 3) + 8 * (r >> 2) + 4 * h;
                const int gm = m0 + wm * 64 + mi * 32 + row;
                C[(size_t)gm * N + gn] = acc[mi][ni][r] * osc + bvv;
            }
        }
    }
}

extern "C" void kernel_launch(void* const* d_in, const int* in_sizes, int n_in,
                              void* d_out, int out_size, void* d_ws, size_t ws_size,
                              hipStream_t stream) {
    const float* x        = (const float*)d_in[0];  // [M][K]
    const float* weight   = (const float*)d_in[1];  // [N][K], fp8-grid values
    const float* w_scale  = (const float*)d_in[2];  // [1]
    const float* bias     = (const float*)d_in[3];  // [N]
    const float* in_scale = (const float*)d_in[4];  // [1]
    float* out = (float*)d_out;

    const int N = in_sizes[3];                 // D_OUT = 4096
    const int K = in_sizes[1] / N;             // D_IN  = 4096
    const int M = in_sizes[0] / K;             // N_TOK = 8192

    uint8_t* qx = (uint8_t*)d_ws;                          // M*K fp8 (32 MB)
    uint8_t* qw = (uint8_t*)d_ws + (size_t)M * K;          // N*K fp8 (16 MB)

    const long nx4   = (long)M * K / 4;        // 8388608, = 16 * 524288
    const long ntot4 = nx4 + (long)N * K / 4;  // + 4194304
    long blks = (ntot4 + 255) / 256; if (blks > 2048) blks = 2048;
    quant_fp8_kernel<<<(int)blks, 256, 0, stream>>>(x, weight, in_scale,
                                                    qx, qw, nx4, ntot4);

    dim3 grid(N / 128, M / 128);  // (32, 64)
    gemm_fp8_kernel<<<grid, 256, 0, stream>>>(qx, qw, bias, in_scale, w_scale,
                                              out, M, N, K);
}